// Round 15
// baseline (251.183 us; speedup 1.0000x reference)
//
#include <hip/hip_runtime.h>
#include <hip/hip_bf16.h>

typedef __attribute__((ext_vector_type(8))) short short8v;   // bf16x8 fragment
typedef __attribute__((ext_vector_type(4))) float float4v;   // fp32x4 accum
typedef unsigned short ushort;
typedef unsigned int uint;

namespace {

constexpr int Hh = 192, Ww = 192, Cc = 16, Oo = 64, Bb = 4;
constexpr int TH = 8, TW = 32, NT = 256;     // 8x32 pixel tile, 256 threads (4 waves)
constexpr int HW = Hh * Ww;                  // 36864
constexpr size_t PLANE = (size_t)Bb * Oo * HW;   // 9437184 floats per partial
constexpr int ER = TH + 22;                  // 30 extended rows
constexpr int ENE = ER * 74;                 // 2220 staged elements

// Each feature = (vertical segment sum) + (horizontal segment sum), scaled by 1/n.
struct FD { int hasV; int vdj, vi0, vi1; int hasH; int hdi, hj0, hj1; float inv_n; };

constexpr FD FT[49] = {
    // 9 inner taps (i,j) row-major, n=1
    {1,-1,-1,-1, 0,0,0,0, 1.f}, {1, 0,-1,-1, 0,0,0,0, 1.f}, {1, 1,-1,-1, 0,0,0,0, 1.f},
    {1,-1, 0, 0, 0,0,0,0, 1.f}, {1, 0, 0, 0, 0,0,0,0, 1.f}, {1, 1, 0, 0, 0,0,0,0, 1.f},
    {1,-1, 1, 1, 0,0,0,0, 1.f}, {1, 0, 1, 1, 0,0,0,0, 1.f}, {1, 1, 1, 1, 0,0,0,0, 1.f},
    // ring5 (16)
    {1,-2,-2, 2, 1,-2,-1, 2, 1.f/9.f},
    {1,-1,-2, 2, 0,0,0,0, 0.2f},
    {1, 0,-2, 2, 0,0,0,0, 0.2f},
    {1, 1,-2, 2, 0,0,0,0, 0.2f},
    {1, 2,-2, 2, 1,-2,-2, 1, 1.f/9.f},
    {0,0,0,0, 1,-1,-2, 2, 0.2f},
    {0,0,0,0, 1,-1,-2, 2, 0.2f},
    {0,0,0,0, 1, 0,-2, 2, 0.2f},
    {0,0,0,0, 1, 0,-2, 2, 0.2f},
    {0,0,0,0, 1, 1,-2, 2, 0.2f},
    {0,0,0,0, 1, 1,-2, 2, 0.2f},
    {1,-2,-2, 2, 1, 2,-1, 2, 1.f/9.f},
    {1,-1,-2, 2, 0,0,0,0, 0.2f},
    {1, 0,-2, 2, 0,0,0,0, 0.2f},
    {1, 1,-2, 2, 0,0,0,0, 0.2f},
    {1, 2,-2, 2, 1, 2,-2, 1, 1.f/9.f},
    // ring7 (24)
    {1,-3,-3,11, 1,-3,-2,21, 1.f/39.f},
    {1,-2,-3,11, 0,0,0,0, 1.f/15.f},
    {1,-1,-3,11, 0,0,0,0, 1.f/15.f},
    {1, 0,-3,11, 0,0,0,0, 1.f/15.f},
    {1, 1,-3,11, 0,0,0,0, 1.f/15.f},
    {1, 2,-3,11, 0,0,0,0, 1.f/15.f},
    {1, 3,-3,11, 1,-3,-21, 2, 1.f/39.f},
    {0,0,0,0, 1,-2,-3,21, 0.04f},
    {0,0,0,0, 1,-2,-21,3, 0.04f},
    {0,0,0,0, 1,-1,-3,21, 0.04f},
    {0,0,0,0, 1,-1,-21,3, 0.04f},
    {0,0,0,0, 1, 0,-3,21, 0.04f},
    {0,0,0,0, 1, 0,-21,3, 0.04f},
    {0,0,0,0, 1, 1,-3,21, 0.04f},
    {0,0,0,0, 1, 1,-21,3, 0.04f},
    {0,0,0,0, 1, 2,-3,21, 0.04f},
    {0,0,0,0, 1, 2,-21,3, 0.04f},
    {1,-3,-11,3, 1, 3,-2,21, 1.f/39.f},
    {1,-2,-11,3, 0,0,0,0, 1.f/15.f},
    {1,-1,-11,3, 0,0,0,0, 1.f/15.f},
    {1, 0,-11,3, 0,0,0,0, 1.f/15.f},
    {1, 1,-11,3, 0,0,0,0, 1.f/15.f},
    {1, 2,-11,3, 0,0,0,0, 1.f/15.f},
    {1, 3,-11,3, 1, 3,-21,2, 1.f/39.f},
};

// reflect-pad(3) + clip index map; valid for u in [-21, 212]
__device__ __forceinline__ int mapIdx(int u) {
    if (u < 0) { u = -u; if (u > 3) u = 3; }
    else if (u > 191) { u = 382 - u; if (u < 188) u = 188; }
    return u;
}

// RNE fp32->bf16 bits (native; pairs fuse to v_cvt_pk_bf16_f32)
__device__ __forceinline__ ushort f2bf(float f) {
    __hip_bfloat16 h = __float2bfloat16(f);
    return __builtin_bit_cast(ushort, h);
}

// LDS layout: union { E[30][76]f (9120) | PVt[31][40]f @9120 (4960) | PHt[14][76]f @14080 (4256) }
//             aliased with featB[256][66]u16 (33792) -> region 33792
// wlds[64][72]u16 (9216) separate.  Total 43008 B -> 3 blocks/CU.
constexpr int OFF_PVT = 30 * 76 * 4;              // 9120
constexpr int OFF_PHT = OFF_PVT + 31 * 40 * 4;    // 14080
constexpr int SM_BYTES = 256 * 66 * 2;            // 33792

// NC = channels per block; DIRECT: write out+bias, else fp32 partial to dst.
template<int NC, bool DIRECT>
__global__ __launch_bounds__(NT, 2)
void fova15(const float* __restrict__ x, const float* __restrict__ wgt,
            const float* __restrict__ bias, float* __restrict__ dst)
{
    constexpr int HALVES = Cc / NC;
    __shared__ __align__(16) char smraw[SM_BYTES];
    __shared__ ushort wlds[64][72];    // bf16 weight slice [o][k], 144B rows (16B-aligned)

    float (*E)[76]      = reinterpret_cast<float(*)[76]>(smraw);
    float (*PVt)[40]    = reinterpret_cast<float(*)[40]>(smraw + OFF_PVT);
    float (*PHt)[76]    = reinterpret_cast<float(*)[76]>(smraw + OFF_PHT);
    ushort (*featB)[66] = reinterpret_cast<ushort(*)[66]>(smraw);

    const int tid  = threadIdx.x;
    const int lane = tid & 63;
    const int wv   = tid >> 6;          // wave id 0..3
    const int w0   = blockIdx.x * TW;
    const int h0   = blockIdx.y * TH;
    const int bz   = blockIdx.z;
    const int b    = (HALVES == 1) ? bz : (bz >> 1);
    const int half = (HALVES == 1) ? 0  : (bz & 1);
    const int c0   = half * NC;
    const int ph   = tid >> 5;          // pixel row 0..7 (tid == pixel id)
    const int pw   = tid & 31;
    const int ur   = ph + 11;           // pixel row in extended coords
    const int vcc  = pw + 21;           // pixel col in extended coords

    float4v acc[4][4];                  // wave wv owns pixels wv*64 .. wv*64+63
#pragma unroll
    for (int i = 0; i < 4; ++i)
#pragma unroll
        for (int j = 0; j < 4; ++j) acc[i][j] = (float4v)(0.f);

    // one-time: zero weight pad slots k=49..63 (never rewritten)
    if (tid < 64) {
#pragma unroll
        for (int f = 49; f < 64; ++f) wlds[tid][f] = 0;
    }

    for (int cc = 0; cc < NC; ++cc) {
        const int c = c0 + cc;
        // ---- phase 1: stage E(c) + stage W(c) into LDS ----
        {
            const float* xp = x + (size_t)(b * Cc + c) * HW;
            for (int idx = tid; idx < ENE; idx += NT) {
                int uu = idx / 74, vvv = idx - uu * 74;
                E[uu][vvv] = xp[mapIdx(h0 + uu - 11) * Ww + mapIdx(w0 + vvv - 21)];
            }
            const float* wc = wgt + c * 49;
            for (int idx = tid; idx < 64 * 49; idx += NT) {
                int o = idx / 49, f = idx - o * 49;
                wlds[o][f] = f2bf(wc[o * 784 + f]);
            }
        }
        __syncthreads();

        // ---- phase 2: serial prefix scans ----
        if (tid < 38) {
            const int cv = tid;           // abs col 18+cv
            float r = 0.f;
            PVt[0][cv] = 0.f;
#pragma unroll
            for (int rr = 0; rr < ER; ++rr) { r += E[rr][18 + cv]; PVt[rr + 1][cv] = r; }
        }
        if (tid >= 96 && tid < 96 + TH + 6) {
            const int rv = tid - 96;      // abs row 8+rv
            float r = 0.f;
            PHt[rv][0] = 0.f;
#pragma unroll
            for (int s = 0; s < 74; ++s) { r += E[8 + rv][s]; PHt[rv][s + 1] = r; }
        }
        __syncthreads();

        // ---- phase 3a: features into registers ----
        float feat[49];
        {
#pragma unroll
            for (int f = 0; f < 49; ++f) {
                float s = 0.f;
                if (FT[f].hasV) {
                    int cv = pw + 3 + FT[f].vdj;
                    s += PVt[ur + FT[f].vi1 + 1][cv] - PVt[ur + FT[f].vi0][cv];
                }
                if (FT[f].hasH) {
                    int rv = ph + 3 + FT[f].hdi;
                    s += PHt[rv][vcc + FT[f].hj1 + 1] - PHt[rv][vcc + FT[f].hj0];
                }
                feat[f] = s * FT[f].inv_n;
            }
        }
        __syncthreads();   // all E/PVt/PHt reads complete before featB overwrites them

        // ---- phase 3b: write featB (aliases E/PVt/PHt region) ----
        {
            uint* fb32 = reinterpret_cast<uint*>(&featB[tid][0]);
#pragma unroll
            for (int j = 0; j < 24; ++j)
                fb32[j] = (uint)f2bf(feat[2 * j]) | ((uint)f2bf(feat[2 * j + 1]) << 16);
            featB[tid][48] = f2bf(feat[48]);
#pragma unroll
            for (int f = 49; f < 64; ++f) featB[tid][f] = 0;
        }
        __syncthreads();

        // ---- phase 4: contraction via MFMA (A from wlds b128, B from featB) ----
        {
            const int olo = lane & 15, kg = lane >> 4;
#pragma unroll
            for (int kc = 0; kc < 2; ++kc) {
                const int k0 = kc * 32 + kg * 8;          // 16B aligned in wlds
                short8v afr[4];
#pragma unroll
                for (int ob = 0; ob < 4; ++ob) {
                    const int o = ob * 16 + olo;
                    afr[ob] = *(const short8v*)(&wlds[o][k0]);
                }
                short8v bfr[4];
#pragma unroll
                for (int nb = 0; nb < 4; ++nb) {
                    const int p = wv * 64 + nb * 16 + olo;
                    const uint* bp = (const uint*)(&featB[p][k0]);
                    uint4 u;
                    u.x = bp[0]; u.y = bp[1]; u.z = bp[2]; u.w = bp[3];
                    bfr[nb] = __builtin_bit_cast(short8v, u);
                }
#pragma unroll
                for (int ob = 0; ob < 4; ++ob)
#pragma unroll
                    for (int nb = 0; nb < 4; ++nb)
                        acc[ob][nb] = __builtin_amdgcn_mfma_f32_16x16x32_bf16(
                            afr[ob], bfr[nb], acc[ob][nb], 0, 0, 0);
            }
        }
        __syncthreads();   // featB (aliased with E) fully read before next stage
    }

    // ---- epilogue: plain stores (partial or final) ----
    float* dbase = DIRECT ? dst : (dst + (size_t)half * PLANE);
#pragma unroll
    for (int ob = 0; ob < 4; ++ob)
#pragma unroll
        for (int nb = 0; nb < 4; ++nb) {
            const int p = wv * 64 + nb * 16 + (lane & 15);
            const int h = h0 + (p >> 5), w = w0 + (p & 31);
            const int o0 = ob * 16 + ((lane >> 4) << 2);
            float4v a = acc[ob][nb];
#pragma unroll
            for (int r = 0; r < 4; ++r) {
                const int o = o0 + r;
                float v = DIRECT ? (a[r] + bias[o]) : a[r];
                dbase[(((size_t)b * Oo + o) * Hh + h) * Ww + w] = v;
            }
        }
}

// out = p0 + p1 + bias (memory-bound, float4, grid-stride)
__global__ __launch_bounds__(256)
void reduce2(const float4* __restrict__ p, const float* __restrict__ bias,
             float4* __restrict__ out)
{
    const int n4 = (int)(PLANE / 4);            // 2359296
    for (int i = blockIdx.x * 256 + threadIdx.x; i < n4; i += gridDim.x * 256) {
        float4 a = p[i];
        float4 b = p[i + n4];
        const int o = (i / 9216) & 63;          // 9216 float4s per (b,o) plane
        const float bo = bias[o];
        float4 r;
        r.x = a.x + b.x + bo; r.y = a.y + b.y + bo;
        r.z = a.z + b.z + bo; r.w = a.w + b.w + bo;
        out[i] = r;
    }
}

} // namespace

extern "C" void kernel_launch(void* const* d_in, const int* in_sizes, int n_in,
                              void* d_out, int out_size, void* d_ws, size_t ws_size,
                              hipStream_t stream) {
    (void)in_sizes; (void)n_in; (void)out_size;
    const float* x    = (const float*)d_in[0];
    const float* wgt  = (const float*)d_in[1];
    const float* bias = (const float*)d_in[2];
    float* out        = (float*)d_out;

    const size_t need = 2 * PLANE * sizeof(float);   // 75.5 MB of partials
    dim3 block(NT);
    if (ws_size >= need) {
        float* part = (float*)d_ws;
        dim3 grid(Ww / TW, Hh / TH, Bb * 2);         // 6 x 24 x 8 = 1152 blocks
        fova15<8, false><<<grid, block, 0, stream>>>(x, wgt, bias, part);
        reduce2<<<dim3(2048), dim3(256), 0, stream>>>((const float4*)part, bias, (float4*)out);
    } else {
        dim3 grid(Ww / TW, Hh / TH, Bb);             // 6 x 24 x 4 = 576 blocks
        fova15<16, true><<<grid, block, 0, stream>>>(x, wgt, bias, out);
    }
}

// Round 16
// 180.685 us; speedup vs baseline: 1.3902x; 1.3902x over previous
//
#include <hip/hip_runtime.h>
#include <hip/hip_bf16.h>

typedef __attribute__((ext_vector_type(8))) short short8v;   // bf16x8 fragment
typedef __attribute__((ext_vector_type(4))) float float4v;   // fp32x4 accum
typedef unsigned short ushort;
typedef unsigned int uint;

namespace {

constexpr int Hh = 192, Ww = 192, Cc = 16, Oo = 64, Bb = 4;
constexpr int TH = 4, TW = 32, NT = 128;     // 4x32 pixel tile, 128 threads (2 waves)
constexpr int HW = Hh * Ww;                  // 36864
constexpr int NPL = Bb * Cc;                 // 64 planes
constexpr int PVG_PLANE = 240 * 198;         // 47520 alloc (236x198 used), col-prefix
constexpr int PHG_PLANE = 198 * 236;         // 46728, row-prefix

// Each feature = (vertical segment sum) + (horizontal segment sum), scaled by 1/n.
struct FD { int hasV; int vdj, vi0, vi1; int hasH; int hdi, hj0, hj1; float inv_n; };

constexpr FD FT[49] = {
    // 9 inner taps (i,j) row-major, n=1 (as V-singles)
    {1,-1,-1,-1, 0,0,0,0, 1.f}, {1, 0,-1,-1, 0,0,0,0, 1.f}, {1, 1,-1,-1, 0,0,0,0, 1.f},
    {1,-1, 0, 0, 0,0,0,0, 1.f}, {1, 0, 0, 0, 0,0,0,0, 1.f}, {1, 1, 0, 0, 0,0,0,0, 1.f},
    {1,-1, 1, 1, 0,0,0,0, 1.f}, {1, 0, 1, 1, 0,0,0,0, 1.f}, {1, 1, 1, 1, 0,0,0,0, 1.f},
    // ring5 (16)
    {1,-2,-2, 2, 1,-2,-1, 2, 1.f/9.f},
    {1,-1,-2, 2, 0,0,0,0, 0.2f},
    {1, 0,-2, 2, 0,0,0,0, 0.2f},
    {1, 1,-2, 2, 0,0,0,0, 0.2f},
    {1, 2,-2, 2, 1,-2,-2, 1, 1.f/9.f},
    {0,0,0,0, 1,-1,-2, 2, 0.2f},
    {0,0,0,0, 1,-1,-2, 2, 0.2f},
    {0,0,0,0, 1, 0,-2, 2, 0.2f},
    {0,0,0,0, 1, 0,-2, 2, 0.2f},
    {0,0,0,0, 1, 1,-2, 2, 0.2f},
    {0,0,0,0, 1, 1,-2, 2, 0.2f},
    {1,-2,-2, 2, 1, 2,-1, 2, 1.f/9.f},
    {1,-1,-2, 2, 0,0,0,0, 0.2f},
    {1, 0,-2, 2, 0,0,0,0, 0.2f},
    {1, 1,-2, 2, 0,0,0,0, 0.2f},
    {1, 2,-2, 2, 1, 2,-2, 1, 1.f/9.f},
    // ring7 (24)
    {1,-3,-3,11, 1,-3,-2,21, 1.f/39.f},
    {1,-2,-3,11, 0,0,0,0, 1.f/15.f},
    {1,-1,-3,11, 0,0,0,0, 1.f/15.f},
    {1, 0,-3,11, 0,0,0,0, 1.f/15.f},
    {1, 1,-3,11, 0,0,0,0, 1.f/15.f},
    {1, 2,-3,11, 0,0,0,0, 1.f/15.f},
    {1, 3,-3,11, 1,-3,-21, 2, 1.f/39.f},
    {0,0,0,0, 1,-2,-3,21, 0.04f},
    {0,0,0,0, 1,-2,-21,3, 0.04f},
    {0,0,0,0, 1,-1,-3,21, 0.04f},
    {0,0,0,0, 1,-1,-21,3, 0.04f},
    {0,0,0,0, 1, 0,-3,21, 0.04f},
    {0,0,0,0, 1, 0,-21,3, 0.04f},
    {0,0,0,0, 1, 1,-3,21, 0.04f},
    {0,0,0,0, 1, 1,-21,3, 0.04f},
    {0,0,0,0, 1, 2,-3,21, 0.04f},
    {0,0,0,0, 1, 2,-21,3, 0.04f},
    {1,-3,-11,3, 1, 3,-2,21, 1.f/39.f},
    {1,-2,-11,3, 0,0,0,0, 1.f/15.f},
    {1,-1,-11,3, 0,0,0,0, 1.f/15.f},
    {1, 0,-11,3, 0,0,0,0, 1.f/15.f},
    {1, 1,-11,3, 0,0,0,0, 1.f/15.f},
    {1, 2,-11,3, 0,0,0,0, 1.f/15.f},
    {1, 3,-11,3, 1, 3,-21,2, 1.f/39.f},
};

// reflect-pad(3) + clip index map; valid for u in [-21, 213]
__device__ __forceinline__ int mapIdx(int u) {
    if (u < 0) { u = -u; if (u > 3) u = 3; }
    else if (u > 191) { u = 382 - u; if (u < 188) u = 188; }
    return u;
}

// RNE fp32->bf16 bits (native; pairs fuse to v_cvt_pk_bf16_f32)
__device__ __forceinline__ ushort f2bf(float f) {
    __hip_bfloat16 h = __float2bfloat16(f);
    return __builtin_bit_cast(ushort, h);
}

// Build global prefix planes.
// PVg[plane][rr][wc], rr in [0,235]: sum over ext rows r'<rr of xext[r'][wc-3]
//   (ext row r' maps to image row mapIdx(r'-21); ext col wc-3 maps via mapIdx)
// PHg[plane][rc][ww], ww in [0,235]: sum over ext cols w'<ww of xext-row
__global__ __launch_bounds__(256)
void prefixes(const float* __restrict__ x, float* __restrict__ pvg,
              float* __restrict__ phg)
{
    const int t = blockIdx.x * 256 + threadIdx.x;      // 0..25343
    const bool isPV = t < NPL * 198;
    const int u = isPV ? t : t - NPL * 198;
    const int plane = u / 198;
    const int q     = u - plane * 198;
    const float* xp = x + (size_t)plane * HW;
    if (isPV) {
        const int wsrc = mapIdx(q - 3);                // fixed source col
        float* pv = pvg + (size_t)plane * PVG_PLANE + q;
        float r = 0.f;
        pv[0] = 0.f;
        for (int rr = 0; rr < 235; ++rr) {
            r += xp[mapIdx(rr - 21) * Ww + wsrc];
            pv[(size_t)(rr + 1) * 198] = r;
        }
    } else {
        const int rsrc = mapIdx(q - 3) * Ww;           // fixed source row
        float* ph = phg + (size_t)plane * PHG_PLANE + (size_t)q * 236;
        float r = 0.f;
        ph[0] = 0.f;
        for (int ww = 0; ww < 235; ++ww) {
            r += xp[rsrc + mapIdx(ww - 21)];
            ph[ww + 1] = r;
        }
    }
}

__global__ __launch_bounds__(NT, 3)
void fova16(const float* __restrict__ wgt, const float* __restrict__ bias,
            const float* __restrict__ pvg, const float* __restrict__ phg,
            float* __restrict__ out)
{
    __shared__ ushort featB[NT][66];   // bf16 feat [pixel][k], padded stride
    __shared__ ushort wlds[64][72];    // bf16 weight slice [o][k], 144B rows

    const int tid  = threadIdx.x;
    const int lane = tid & 63;
    const int wv   = tid >> 6;          // wave id 0/1
    const int w0   = blockIdx.x * TW;
    const int h0   = blockIdx.y * TH;
    const int b    = blockIdx.z;
    const int ph_  = tid >> 5;          // pixel row 0..3 (tid == pixel id)
    const int pw   = tid & 31;
    const int h    = h0 + ph_, w = w0 + pw;

    float4v acc[4][4];
#pragma unroll
    for (int i = 0; i < 4; ++i)
#pragma unroll
        for (int j = 0; j < 4; ++j) acc[i][j] = (float4v)(0.f);

    // one-time pad zeroing (ordered before first MFMA by the in-loop barrier)
#pragma unroll
    for (int f = 49; f < 64; ++f) featB[tid][f] = 0;
    if (tid < 64) {
#pragma unroll
        for (int f = 49; f < 64; ++f) wlds[tid][f] = 0;
    }

    // per-thread prefix bases (c-invariant structure; +plane stride per c)
    const float* pvb = pvg + (size_t)(b * Cc) * PVG_PLANE + (size_t)(h + 22) * 198 + (w + 3);
    const float* phb = phg + (size_t)(b * Cc) * PHG_PLANE + (size_t)(h + 3) * 236 + (w + 21);

    for (int c = 0; c < Cc; ++c) {
        // ---- stage W(c) into LDS ----
        {
            const float* wc = wgt + c * 49;
            for (int idx = tid; idx < 64 * 49; idx += NT) {
                int o = idx / 49, f = idx - o * 49;
                wlds[o][f] = f2bf(wc[o * 784 + f]);
            }
        }
        // ---- features straight from prefix planes (const-imm offsets) ----
        {
            const float* pv = pvb;
            const float* phv = phb;
            auto FV = [&](int f) -> float {
                float s = 0.f;
                if (FT[f].hasV) {
                    // rows [h+vi0, h+vi1] at col w+vdj
                    s += pv[FT[f].vi1 * 198 + FT[f].vdj] - pv[(FT[f].vi0 - 1) * 198 + FT[f].vdj];
                }
                if (FT[f].hasH) {
                    // cols [w+hj0, w+hj1] at row h+hdi
                    s += phv[FT[f].hdi * 236 + (FT[f].hj1 + 1)] - phv[FT[f].hdi * 236 + FT[f].hj0];
                }
                return s * FT[f].inv_n;
            };
            uint* fb32 = reinterpret_cast<uint*>(&featB[tid][0]);
#pragma unroll
            for (int j = 0; j < 24; ++j)
                fb32[j] = (uint)f2bf(FV(2 * j)) | ((uint)f2bf(FV(2 * j + 1)) << 16);
            featB[tid][48] = f2bf(FV(48));
        }
        __syncthreads();

        // ---- MFMA(c): A from wlds (b128), B from featB ----
        {
            const int olo = lane & 15, kg = lane >> 4;
#pragma unroll
            for (int kc = 0; kc < 2; ++kc) {
                const int k0 = kc * 32 + kg * 8;          // 16B aligned in wlds
                short8v afr[4];
#pragma unroll
                for (int ob = 0; ob < 4; ++ob) {
                    const int o = ob * 16 + olo;
                    afr[ob] = *(const short8v*)(&wlds[o][k0]);
                }
                short8v bfr[4];
#pragma unroll
                for (int nb = 0; nb < 4; ++nb) {
                    const int p = wv * 64 + nb * 16 + olo;
                    const uint* bp = (const uint*)(&featB[p][k0]);
                    uint4 u;
                    u.x = bp[0]; u.y = bp[1]; u.z = bp[2]; u.w = bp[3];
                    bfr[nb] = __builtin_bit_cast(short8v, u);
                }
#pragma unroll
                for (int ob = 0; ob < 4; ++ob)
#pragma unroll
                    for (int nb = 0; nb < 4; ++nb)
                        acc[ob][nb] = __builtin_amdgcn_mfma_f32_16x16x32_bf16(
                            afr[ob], bfr[nb], acc[ob][nb], 0, 0, 0);
            }
        }
        __syncthreads();   // featB/wlds rewritten next c

        pvb += PVG_PLANE; phb += PHG_PLANE;
    }

    // ---- epilogue: D frag: col(pixel)=lane&15, row(o)=(lane>>4)*4+reg ----
#pragma unroll
    for (int ob = 0; ob < 4; ++ob)
#pragma unroll
        for (int nb = 0; nb < 4; ++nb) {
            const int p = wv * 64 + nb * 16 + (lane & 15);
            const int hh = h0 + (p >> 5), ww2 = w0 + (p & 31);
            const int o0 = ob * 16 + ((lane >> 4) << 2);
            float4v a = acc[ob][nb];
#pragma unroll
            for (int r = 0; r < 4; ++r) {
                const int o = o0 + r;
                out[(((size_t)b * Oo + o) * Hh + hh) * Ww + ww2] = a[r] + bias[o];
            }
        }
}

} // namespace

extern "C" void kernel_launch(void* const* d_in, const int* in_sizes, int n_in,
                              void* d_out, int out_size, void* d_ws, size_t ws_size,
                              hipStream_t stream) {
    (void)in_sizes; (void)n_in; (void)out_size; (void)ws_size;
    const float* x    = (const float*)d_in[0];
    const float* wgt  = (const float*)d_in[1];
    const float* bias = (const float*)d_in[2];
    float* out        = (float*)d_out;

    float* pvg = (float*)d_ws;                        // 64 * 47520 floats
    float* phg = pvg + (size_t)NPL * PVG_PLANE;       // 64 * 46728 floats (total 24.1 MB)

    prefixes<<<dim3((2 * NPL * 198 + 255) / 256), dim3(256), 0, stream>>>(x, pvg, phg);

    dim3 grid(Ww / TW, Hh / TH, Bb);                  // 6 x 48 x 4 = 1152 blocks
    fova16<<<grid, dim3(NT), 0, stream>>>(wgt, bias, pvg, phg, out);
}

// Round 17
// 130.054 us; speedup vs baseline: 1.9314x; 1.3893x over previous
//
#include <hip/hip_runtime.h>
#include <hip/hip_bf16.h>

typedef __attribute__((ext_vector_type(8))) short short8v;   // bf16x8 fragment
typedef __attribute__((ext_vector_type(4))) float float4v;   // fp32x4 accum
typedef unsigned short ushort;
typedef unsigned int uint;

namespace {

constexpr int Hh = 192, Ww = 192, Cc = 16, Oo = 64, Bb = 4;
constexpr int TH = 4, TW = 32, NT = 128;     // 4x32 pixel tile, 128 threads (2 waves)
constexpr int HW = Hh * Ww;                  // 36864
constexpr int NPL = Bb * Cc;                 // 64 planes
constexpr int PVG_PLANE = 240 * 198;         // col-prefix plane (236x198 used)
constexpr int PHG_PLANE = 198 * 236;         // row-prefix plane
constexpr size_t PLANE = (size_t)Bb * Oo * HW;                 // 9437184 floats
constexpr size_t PREFIX_FLOATS = (size_t)NPL * (PVG_PLANE + PHG_PLANE);
constexpr size_t NEED_PREFIX = PREFIX_FLOATS * 4;              // 24,127,488 B
constexpr size_t NEED_FULL   = NEED_PREFIX + 2 * PLANE * 4;    // 99,624,960 B

// Each feature = (vertical segment sum) + (horizontal segment sum), scaled by 1/n.
struct FD { int hasV; int vdj, vi0, vi1; int hasH; int hdi, hj0, hj1; float inv_n; };

constexpr FD FT[49] = {
    // 9 inner taps (i,j) row-major, n=1 (as V-singles)
    {1,-1,-1,-1, 0,0,0,0, 1.f}, {1, 0,-1,-1, 0,0,0,0, 1.f}, {1, 1,-1,-1, 0,0,0,0, 1.f},
    {1,-1, 0, 0, 0,0,0,0, 1.f}, {1, 0, 0, 0, 0,0,0,0, 1.f}, {1, 1, 0, 0, 0,0,0,0, 1.f},
    {1,-1, 1, 1, 0,0,0,0, 1.f}, {1, 0, 1, 1, 0,0,0,0, 1.f}, {1, 1, 1, 1, 0,0,0,0, 1.f},
    // ring5 (16)
    {1,-2,-2, 2, 1,-2,-1, 2, 1.f/9.f},
    {1,-1,-2, 2, 0,0,0,0, 0.2f},
    {1, 0,-2, 2, 0,0,0,0, 0.2f},
    {1, 1,-2, 2, 0,0,0,0, 0.2f},
    {1, 2,-2, 2, 1,-2,-2, 1, 1.f/9.f},
    {0,0,0,0, 1,-1,-2, 2, 0.2f},
    {0,0,0,0, 1,-1,-2, 2, 0.2f},
    {0,0,0,0, 1, 0,-2, 2, 0.2f},
    {0,0,0,0, 1, 0,-2, 2, 0.2f},
    {0,0,0,0, 1, 1,-2, 2, 0.2f},
    {0,0,0,0, 1, 1,-2, 2, 0.2f},
    {1,-2,-2, 2, 1, 2,-1, 2, 1.f/9.f},
    {1,-1,-2, 2, 0,0,0,0, 0.2f},
    {1, 0,-2, 2, 0,0,0,0, 0.2f},
    {1, 1,-2, 2, 0,0,0,0, 0.2f},
    {1, 2,-2, 2, 1, 2,-2, 1, 1.f/9.f},
    // ring7 (24)
    {1,-3,-3,11, 1,-3,-2,21, 1.f/39.f},
    {1,-2,-3,11, 0,0,0,0, 1.f/15.f},
    {1,-1,-3,11, 0,0,0,0, 1.f/15.f},
    {1, 0,-3,11, 0,0,0,0, 1.f/15.f},
    {1, 1,-3,11, 0,0,0,0, 1.f/15.f},
    {1, 2,-3,11, 0,0,0,0, 1.f/15.f},
    {1, 3,-3,11, 1,-3,-21, 2, 1.f/39.f},
    {0,0,0,0, 1,-2,-3,21, 0.04f},
    {0,0,0,0, 1,-2,-21,3, 0.04f},
    {0,0,0,0, 1,-1,-3,21, 0.04f},
    {0,0,0,0, 1,-1,-21,3, 0.04f},
    {0,0,0,0, 1, 0,-3,21, 0.04f},
    {0,0,0,0, 1, 0,-21,3, 0.04f},
    {0,0,0,0, 1, 1,-3,21, 0.04f},
    {0,0,0,0, 1, 1,-21,3, 0.04f},
    {0,0,0,0, 1, 2,-3,21, 0.04f},
    {0,0,0,0, 1, 2,-21,3, 0.04f},
    {1,-3,-11,3, 1, 3,-2,21, 1.f/39.f},
    {1,-2,-11,3, 0,0,0,0, 1.f/15.f},
    {1,-1,-11,3, 0,0,0,0, 1.f/15.f},
    {1, 0,-11,3, 0,0,0,0, 1.f/15.f},
    {1, 1,-11,3, 0,0,0,0, 1.f/15.f},
    {1, 2,-11,3, 0,0,0,0, 1.f/15.f},
    {1, 3,-11,3, 1, 3,-21,2, 1.f/39.f},
};

// reflect-pad(3) + clip index map; valid for u in [-21, 213]
__device__ __forceinline__ int mapIdx(int u) {
    if (u < 0) { u = -u; if (u > 3) u = 3; }
    else if (u > 191) { u = 382 - u; if (u < 188) u = 188; }
    return u;
}

// RNE fp32->bf16 bits (native; pairs fuse to v_cvt_pk_bf16_f32)
__device__ __forceinline__ ushort f2bf(float f) {
    __hip_bfloat16 h = __float2bfloat16(f);
    return __builtin_bit_cast(ushort, h);
}

// Build global prefix planes; 64-thread blocks (CU spread), 5-wide unrolled scans.
__global__ __launch_bounds__(64)
void prefixes(const float* __restrict__ x, float* __restrict__ pvg,
              float* __restrict__ phg)
{
    const int t = blockIdx.x * 64 + threadIdx.x;       // 0..25343
    if (t >= 2 * NPL * 198) return;
    const bool isPV = t < NPL * 198;
    const int u = isPV ? t : t - NPL * 198;
    const int plane = u / 198;
    const int q     = u - plane * 198;
    const float* xp = x + (size_t)plane * HW;
    if (isPV) {
        const int wsrc = mapIdx(q - 3);                // fixed source col
        float* pv = pvg + (size_t)plane * PVG_PLANE + q;
        float r = 0.f;
        pv[0] = 0.f;
        for (int t0 = 0; t0 < 235; t0 += 5) {          // 47 groups; 5 loads batched
            float v0 = xp[mapIdx(t0 - 21) * Ww + wsrc];
            float v1 = xp[mapIdx(t0 - 20) * Ww + wsrc];
            float v2 = xp[mapIdx(t0 - 19) * Ww + wsrc];
            float v3 = xp[mapIdx(t0 - 18) * Ww + wsrc];
            float v4 = xp[mapIdx(t0 - 17) * Ww + wsrc];
            float* pd = pv + (size_t)(t0 + 1) * 198;
            r += v0; pd[0]   = r;
            r += v1; pd[198] = r;
            r += v2; pd[396] = r;
            r += v3; pd[594] = r;
            r += v4; pd[792] = r;
        }
    } else {
        const int rsrc = mapIdx(q - 3) * Ww;           // fixed source row
        float* ph = phg + (size_t)plane * PHG_PLANE + (size_t)q * 236;
        float r = 0.f;
        ph[0] = 0.f;
        for (int t0 = 0; t0 < 235; t0 += 5) {
            float v0 = xp[rsrc + mapIdx(t0 - 21)];
            float v1 = xp[rsrc + mapIdx(t0 - 20)];
            float v2 = xp[rsrc + mapIdx(t0 - 19)];
            float v3 = xp[rsrc + mapIdx(t0 - 18)];
            float v4 = xp[rsrc + mapIdx(t0 - 17)];
            float* pd = ph + t0 + 1;
            r += v0; pd[0] = r;
            r += v1; pd[1] = r;
            r += v2; pd[2] = r;
            r += v3; pd[3] = r;
            r += v4; pd[4] = r;
        }
    }
}

// NC = channels per block; DIRECT: write out+bias, else fp32 partial to dst.
template<int NC, bool DIRECT>
__global__ __launch_bounds__(NT, 3)
void fova17(const float* __restrict__ wgt, const float* __restrict__ bias,
            const float* __restrict__ pvg, const float* __restrict__ phg,
            float* __restrict__ dst)
{
    constexpr int HALVES = Cc / NC;
    __shared__ ushort featB[NT][66];   // bf16 feat [pixel][k], padded stride
    __shared__ ushort wlds[64][72];    // bf16 weight slice [o][k], 144B rows

    const int tid  = threadIdx.x;
    const int lane = tid & 63;
    const int wv   = tid >> 6;          // wave id 0/1
    const int w0   = blockIdx.x * TW;
    const int h0   = blockIdx.y * TH;
    const int bz   = blockIdx.z;
    const int b    = (HALVES == 1) ? bz : (bz >> 1);
    const int half = (HALVES == 1) ? 0  : (bz & 1);
    const int c0   = half * NC;
    const int ph_  = tid >> 5;          // pixel row 0..3 (tid == pixel id)
    const int pw   = tid & 31;
    const int h    = h0 + ph_, w = w0 + pw;

    float4v acc[4][4];
#pragma unroll
    for (int i = 0; i < 4; ++i)
#pragma unroll
        for (int j = 0; j < 4; ++j) acc[i][j] = (float4v)(0.f);

    // one-time pad zeroing (ordered before first MFMA by the in-loop barrier)
#pragma unroll
    for (int f = 49; f < 64; ++f) featB[tid][f] = 0;
    if (tid < 64) {
#pragma unroll
        for (int f = 49; f < 64; ++f) wlds[tid][f] = 0;
    }

    // per-thread prefix bases (plane stride advanced per c)
    const float* pvb = pvg + (size_t)(b * Cc + c0) * PVG_PLANE + (size_t)(h + 22) * 198 + (w + 3);
    const float* phb = phg + (size_t)(b * Cc + c0) * PHG_PLANE + (size_t)(h + 3) * 236 + (w + 21);

    for (int cc = 0; cc < NC; ++cc) {
        // ---- stage W(c) into LDS ----
        {
            const float* wc = wgt + (c0 + cc) * 49;
            for (int idx = tid; idx < 64 * 49; idx += NT) {
                int o = idx / 49, f = idx - o * 49;
                wlds[o][f] = f2bf(wc[o * 784 + f]);
            }
        }
        // ---- features straight from prefix planes (const-imm offsets) ----
        {
            const float* pv = pvb;
            const float* phv = phb;
            auto FV = [&](int f) -> float {
                float s = 0.f;
                if (FT[f].hasV) {
                    s += pv[FT[f].vi1 * 198 + FT[f].vdj] - pv[(FT[f].vi0 - 1) * 198 + FT[f].vdj];
                }
                if (FT[f].hasH) {
                    s += phv[FT[f].hdi * 236 + (FT[f].hj1 + 1)] - phv[FT[f].hdi * 236 + FT[f].hj0];
                }
                return s * FT[f].inv_n;
            };
            uint* fb32 = reinterpret_cast<uint*>(&featB[tid][0]);
#pragma unroll
            for (int j = 0; j < 24; ++j)
                fb32[j] = (uint)f2bf(FV(2 * j)) | ((uint)f2bf(FV(2 * j + 1)) << 16);
            featB[tid][48] = f2bf(FV(48));
        }
        __syncthreads();

        // ---- MFMA(c): A from wlds (b128), B from featB ----
        {
            const int olo = lane & 15, kg = lane >> 4;
#pragma unroll
            for (int kc = 0; kc < 2; ++kc) {
                const int k0 = kc * 32 + kg * 8;          // 16B aligned in wlds
                short8v afr[4];
#pragma unroll
                for (int ob = 0; ob < 4; ++ob) {
                    const int o = ob * 16 + olo;
                    afr[ob] = *(const short8v*)(&wlds[o][k0]);
                }
                short8v bfr[4];
#pragma unroll
                for (int nb = 0; nb < 4; ++nb) {
                    const int p = wv * 64 + nb * 16 + olo;
                    const uint* bp = (const uint*)(&featB[p][k0]);
                    uint4 u;
                    u.x = bp[0]; u.y = bp[1]; u.z = bp[2]; u.w = bp[3];
                    bfr[nb] = __builtin_bit_cast(short8v, u);
                }
#pragma unroll
                for (int ob = 0; ob < 4; ++ob)
#pragma unroll
                    for (int nb = 0; nb < 4; ++nb)
                        acc[ob][nb] = __builtin_amdgcn_mfma_f32_16x16x32_bf16(
                            afr[ob], bfr[nb], acc[ob][nb], 0, 0, 0);
            }
        }
        __syncthreads();   // featB/wlds rewritten next c

        pvb += PVG_PLANE; phb += PHG_PLANE;
    }

    // ---- epilogue: D frag: col(pixel)=lane&15, row(o)=(lane>>4)*4+reg ----
    float* dbase = DIRECT ? dst : (dst + (size_t)half * PLANE);
#pragma unroll
    for (int ob = 0; ob < 4; ++ob)
#pragma unroll
        for (int nb = 0; nb < 4; ++nb) {
            const int p = wv * 64 + nb * 16 + (lane & 15);
            const int hh = h0 + (p >> 5), ww2 = w0 + (p & 31);
            const int o0 = ob * 16 + ((lane >> 4) << 2);
            float4v a = acc[ob][nb];
#pragma unroll
            for (int r = 0; r < 4; ++r) {
                const int o = o0 + r;
                float v = DIRECT ? (a[r] + bias[o]) : a[r];
                dbase[(((size_t)b * Oo + o) * Hh + hh) * Ww + ww2] = v;
            }
        }
}

// out = p0 + p1 + bias (memory-bound, float4, grid-stride)
__global__ __launch_bounds__(256)
void reduce2(const float4* __restrict__ p, const float* __restrict__ bias,
             float4* __restrict__ out)
{
    const int n4 = (int)(PLANE / 4);            // 2359296
    for (int i = blockIdx.x * 256 + threadIdx.x; i < n4; i += gridDim.x * 256) {
        float4 a = p[i];
        float4 b = p[i + n4];
        const int o = (i / 9216) & 63;          // 9216 float4s per (b,o) plane
        const float bo = bias[o];
        float4 r;
        r.x = a.x + b.x + bo; r.y = a.y + b.y + bo;
        r.z = a.z + b.z + bo; r.w = a.w + b.w + bo;
        out[i] = r;
    }
}

} // namespace

extern "C" void kernel_launch(void* const* d_in, const int* in_sizes, int n_in,
                              void* d_out, int out_size, void* d_ws, size_t ws_size,
                              hipStream_t stream) {
    (void)in_sizes; (void)n_in; (void)out_size;
    const float* x    = (const float*)d_in[0];
    const float* wgt  = (const float*)d_in[1];
    const float* bias = (const float*)d_in[2];
    float* out        = (float*)d_out;

    float* pvg = (float*)d_ws;
    float* phg = pvg + (size_t)NPL * PVG_PLANE;

    prefixes<<<dim3((2 * NPL * 198 + 63) / 64), dim3(64), 0, stream>>>(x, pvg, phg);

    dim3 block(NT);
    if (ws_size >= NEED_FULL) {
        float* part = (float*)d_ws + PREFIX_FLOATS;
        dim3 grid(Ww / TW, Hh / TH, Bb * 2);          // 2304 blocks, 8 channels each
        fova17<8, false><<<grid, block, 0, stream>>>(wgt, bias, pvg, phg, part);
        reduce2<<<dim3(2048), dim3(256), 0, stream>>>((const float4*)part, bias, (float4*)out);
    } else {
        dim3 grid(Ww / TW, Hh / TH, Bb);              // 1152 blocks, 16 channels
        fova17<16, true><<<grid, block, 0, stream>>>(wgt, bias, pvg, phg, out);
    }
}